// Round 10
// baseline (308.856 us; speedup 1.0000x reference)
//
#include <hip/hip_runtime.h>
#include <hip/hip_fp16.h>

// LFM2 short-conv block. Round 10: ONE barrier per K-tile (was 4). Stages issued at
// tile top, drained by a fully-aged vmcnt(0) at tile end; quadrant MFMAs synced only
// by wave-local lgkmcnt(0). Register choreography identical to r9 (VGPR 112, no spill).

typedef _Float16 f16x8 __attribute__((ext_vector_type(8)));
typedef float    f32x4 __attribute__((ext_vector_type(4)));

#define GLD_LDS16(gsrc, sdst) \
  __builtin_amdgcn_global_load_lds((const __attribute__((address_space(1))) void*)(gsrc), \
                                   (__attribute__((address_space(3))) void*)(sdst), 16, 0, 0)

#define VMCNT0 asm volatile("s_waitcnt vmcnt(0)" ::: "memory")
#define LGKM0  asm volatile("s_waitcnt lgkmcnt(0)" ::: "memory")
#define BAR    __builtin_amdgcn_s_barrier()
#define SCHED0 __builtin_amdgcn_sched_barrier(0)

// ---------------- fused fp32 -> fp16 convert of X, W_in, W_out ----------------
__global__ __launch_bounds__(256) void cvt_all(const float* __restrict__ X,
                                               const float* __restrict__ Wi,
                                               const float* __restrict__ Wo,
                                               _Float16* __restrict__ Xh,
                                               _Float16* __restrict__ Wih,
                                               _Float16* __restrict__ Woh) {
  int base = (blockIdx.x * 256 + threadIdx.x) * 8;   // total 33,554,432 elems
  const float* src;
  _Float16* dst;
  int off;
  if (base < 16777216)      { src = X;  dst = Xh;  off = base; }
  else if (base < 29360128) { src = Wi; dst = Wih; off = base - 16777216; }
  else                      { src = Wo; dst = Woh; off = base - 29360128; }
  const float4* p = reinterpret_cast<const float4*>(src + off);
  float4 a = p[0], b = p[1];
  f16x8 o;
  o[0] = (_Float16)a.x; o[1] = (_Float16)a.y; o[2] = (_Float16)a.z; o[3] = (_Float16)a.w;
  o[4] = (_Float16)b.x; o[5] = (_Float16)b.y; o[6] = (_Float16)b.z; o[7] = (_Float16)b.w;
  *reinterpret_cast<f16x8*>(dst + off) = o;
}

// ---------------- conv + gating: y = Cg * causal_conv3(Bg * x) ----------------
__global__ __launch_bounds__(256) void conv_gate(const _Float16* __restrict__ BCx,
                                                 const float* __restrict__ Wc,   // [2048,1,3]
                                                 _Float16* __restrict__ Y) {
  const int h0 = threadIdx.x * 8;
  const int r0 = blockIdx.x * 8;
  const int s0 = r0 & 4095;

  float w0[8], w1[8], w2[8];
#pragma unroll
  for (int j = 0; j < 8; ++j) {
    w0[j] = Wc[(h0 + j) * 3 + 0];
    w1[j] = Wc[(h0 + j) * 3 + 1];
    w2[j] = Wc[(h0 + j) * 3 + 2];
  }

  float bxm2[8] = {}, bxm1[8] = {};
  if (s0 != 0) {
    const _Float16* pm2 = BCx + (size_t)(r0 - 2) * 6144 + h0;
    const _Float16* pm1 = BCx + (size_t)(r0 - 1) * 6144 + h0;
    f16x8 bg2 = *reinterpret_cast<const f16x8*>(pm2);
    f16x8 xx2 = *reinterpret_cast<const f16x8*>(pm2 + 4096);
    f16x8 bg1 = *reinterpret_cast<const f16x8*>(pm1);
    f16x8 xx1 = *reinterpret_cast<const f16x8*>(pm1 + 4096);
#pragma unroll
    for (int j = 0; j < 8; ++j) {
      bxm2[j] = (float)bg2[j] * (float)xx2[j];
      bxm1[j] = (float)bg1[j] * (float)xx1[j];
    }
  }

  for (int i = 0; i < 8; ++i) {
    const _Float16* pr = BCx + (size_t)(r0 + i) * 6144 + h0;
    f16x8 bg = *reinterpret_cast<const f16x8*>(pr);
    f16x8 cg = *reinterpret_cast<const f16x8*>(pr + 2048);
    f16x8 xx = *reinterpret_cast<const f16x8*>(pr + 4096);
    f16x8 o;
#pragma unroll
    for (int j = 0; j < 8; ++j) {
      float bx   = (float)bg[j] * (float)xx[j];
      float conv = w0[j] * bxm2[j] + w1[j] * bxm1[j] + w2[j] * bx;
      o[j] = (_Float16)((float)cg[j] * conv);
      bxm2[j] = bxm1[j];
      bxm1[j] = bx;
    }
    *reinterpret_cast<f16x8*>(Y + (size_t)(r0 + i) * 2048 + h0) = o;
  }
}

// ---------------- fragment load helpers ----------------
__device__ __forceinline__ void ldA(f16x8 (&af)[4][2], const _Float16* p, int base, int ak0, int ak1) {
#pragma unroll
  for (int i = 0; i < 4; ++i) {
    af[i][0] = *(const f16x8*)(p + base + i * 1024 + ak0);
    af[i][1] = *(const f16x8*)(p + base + i * 1024 + ak1);
  }
}
__device__ __forceinline__ void ldB(f16x8 (&bf)[2][2], const _Float16* p, int base, int ak0, int ak1) {
#pragma unroll
  for (int j = 0; j < 2; ++j) {
    bf[j][0] = *(const f16x8*)(p + base + j * 1024 + ak0);
    bf[j][1] = *(const f16x8*)(p + base + j * 1024 + ak1);
  }
}
template <int QM, int QN>
__device__ __forceinline__ void mfmaQ(f32x4 (&acc)[8][4], const f16x8 (&af)[4][2], const f16x8 (&bf)[2][2]) {
  __builtin_amdgcn_s_setprio(1);
#pragma unroll
  for (int i = 0; i < 4; ++i)
#pragma unroll
    for (int j = 0; j < 2; ++j)
#pragma unroll
      for (int ks = 0; ks < 2; ++ks)
        acc[QM * 4 + i][QN * 2 + j] =
            __builtin_amdgcn_mfma_f32_16x16x32_f16(af[i][ks], bf[j][ks], acc[QM * 4 + i][QN * 2 + j], 0, 0, 0);
  __builtin_amdgcn_s_setprio(0);
}

// 256x256 NT GEMM, BK=64, 8 waves (2x4), 16x16x32 MFMA, 128KB static LDS.
// A LDS [256][64] fp16, phys 16B-chunk ^= (row&7) [T2]; gld_lds linear dest +
// inverse-swizzled per-lane SOURCE (rule 21).
// ONE barrier per tile. Tile body:
//   1. stage all 8 DMA units -> next buffer          (issued EARLY)
//   2. lgkm0; Q00(afL,bf0); ldB bf<-bf1(c)
//   3. lgkm0; Q01(afL,bf1); ldA af<-afH(c)
//   4. lgkm0; Q11(afH,bf1); ldB bf<-bf0(c)
//   5. lgkm0; Q10(afH,bf0)
//   6. vmcnt(0)  [stages aged ~3000 cy -> free]; BAR  [publishes next buffer]
//   7. ldA af<-afL(next); ldB bf<-bf0(next)           (prefetch for next tile)
// Cross-wave audit: all current-buffer reads lgkm-complete before each wave's BAR
// arrival (step-5 lgkm0); stages into next retired by own vmcnt0 pre-BAR; overwrite
// of current happens next tile AFTER the barrier. Every dependency spans the BAR.
// ARGS: N = C column stride, K = reduction dim, nbn = N/256.
template <typename CT>
__global__ __launch_bounds__(512, 2) void gemm8p(const _Float16* __restrict__ Ag,
                                                 const _Float16* __restrict__ Bg,
                                                 CT* __restrict__ Cg,
                                                 int N, int K, int nbn) {
  __shared__ __align__(16) char smem[131072];
  const int tid = threadIdx.x, lane = tid & 63, w = tid >> 6;
  const int wr = w >> 2, wc = w & 3;

  // T1: XCD-bijective block swizzle (grid % 8 == 0)
  const int nwg = (int)gridDim.x, q8 = nwg >> 3;
  const int swz = ((int)blockIdx.x & 7) * q8 + ((int)blockIdx.x >> 3);
  const int bm = (swz / nbn) << 8, bn = (swz % nbn) << 8;

  _Float16* const A0 = (_Float16*)(smem);
  _Float16* const B0 = (_Float16*)(smem + 32768);
  _Float16* const A1 = (_Float16*)(smem + 65536);
  _Float16* const B1 = (_Float16*)(smem + 98304);

  const int rr = tid >> 3;
  const int sCol = ((tid & 7) ^ (rr & 7)) * 8;                  // inverse-swizzled source chunk
  const _Float16* aSrc = Ag + (size_t)(bm + rr) * K + sCol;
  const _Float16* bSrc = Bg + (size_t)(bn + (rr >> 5) * 64 + (rr & 31)) * K + sCol;

  // read-side swizzle folds to per-lane constants (row&7 == lane&7 for all read rows)
  const int ak0 = ((lane >> 4) ^ (lane & 7)) * 8;
  const int ak1 = (((lane >> 4) + 4) ^ (lane & 7)) * 8;
  const int aRB = (wr * 128 + (lane & 15)) * 64;
  const int bRB = (wc * 32 + (lane & 15)) * 64;

  const int nt = K >> 6;

#define STG_A(NBO, kt, u) GLD_LDS16(aSrc + (size_t)(u) * 64 * K + (kt) * 64, \
                                    smem + (NBO) + (u) * 8192 + tid * 16)
#define STG_B(NBO, kt, u) GLD_LDS16(bSrc + (size_t)(((u) & 1) * 128 + ((u) >> 1) * 32) * K + (kt) * 64, \
                                    smem + (NBO) + 32768 + (u) * 8192 + tid * 16)

  f16x8 af[4][2], bf[2][2];
  f32x4 acc[8][4] = {};

  // prologue: stage tile 0 -> buffer 0, drain, pre-read afL(0), bf0(0)
  STG_A(0, 0, 0); STG_A(0, 0, 2);
  STG_B(0, 0, 0); STG_B(0, 0, 1);
  STG_B(0, 0, 2); STG_B(0, 0, 3);
  STG_A(0, 0, 1); STG_A(0, 0, 3);
  VMCNT0; BAR;
  ldA(af, A0, aRB, ak0, ak1);
  ldB(bf, B0, bRB, ak0, ak1);

#define TILE(AB, BB, ABn, BBn, NBO, t)                             \
  {                                                                \
    const int tn = ((t) + 1 < nt) ? (t) + 1 : nt - 1;              \
    /* 1: stage whole next tile into next buffer */                \
    STG_A(NBO, tn, 0); STG_A(NBO, tn, 2);                          \
    STG_B(NBO, tn, 0); STG_B(NBO, tn, 1);                          \
    STG_B(NBO, tn, 2); STG_B(NBO, tn, 3);                          \
    STG_A(NBO, tn, 1); STG_A(NBO, tn, 3);                          \
    /* 2: Q00(afL,bf0); reload bf<-bf1(c) */                       \
    LGKM0; SCHED0;                                                 \
    mfmaQ<0, 0>(acc, af, bf);                                      \
    ldB(bf, BB, bRB + 8192, ak0, ak1);                             \
    /* 3: Q01(afL,bf1); reload af<-afH(c) */                       \
    LGKM0; SCHED0;                                                 \
    mfmaQ<0, 1>(acc, af, bf);                                      \
    ldA(af, AB, aRB + 4096, ak0, ak1);                             \
    /* 4: Q11(afH,bf1); reload bf<-bf0(c) */                       \
    LGKM0; SCHED0;                                                 \
    mfmaQ<1, 1>(acc, af, bf);                                      \
    ldB(bf, BB, bRB, ak0, ak1);                                    \
    /* 5: Q10(afH,bf0) */                                          \
    LGKM0; SCHED0;                                                 \
    mfmaQ<1, 0>(acc, af, bf);                                      \
    /* 6: aged drain + single barrier (publishes next buffer) */   \
    VMCNT0; BAR;                                                   \
    /* 7: prefetch next tile's afL, bf0 from next buffer */        \
    ldA(af, ABn, aRB, ak0, ak1);                                   \
    ldB(bf, BBn, bRB, ak0, ak1);                                   \
  }

  for (int t = 0; t < nt; t += 2) {
    TILE(A0, B0, A1, B1, 65536, t);
    TILE(A1, B1, A0, B0, 0, t + 1);
  }
  LGKM0; VMCNT0;  // drain trailing prefetch reads + tail restage

  // epilogue: D row=(lane>>4)*4+reg, col=lane&15
  const int rb = bm + wr * 128 + ((lane >> 4) << 2);
  const int cb = bn + wc * 64 + (lane & 15);
#pragma unroll
  for (int mi = 0; mi < 8; ++mi)
#pragma unroll
    for (int nj = 0; nj < 4; ++nj) {
      f32x4 v = acc[mi][nj];
#pragma unroll
      for (int rg = 0; rg < 4; ++rg)
        Cg[(size_t)(rb + mi * 16 + rg) * N + cb + nj * 16] = (CT)v[rg];
    }
#undef TILE
#undef STG_A
#undef STG_B
}

// ---------------- launcher ----------------
extern "C" void kernel_launch(void* const* d_in, const int* in_sizes, int n_in,
                              void* d_out, int out_size, void* d_ws, size_t ws_size,
                              hipStream_t stream) {
  const float* X  = (const float*)d_in[0];  // [2,4096,2048]
  const float* Wi = (const float*)d_in[1];  // [6144,2048]
  const float* Wc = (const float*)d_in[2];  // [2048,1,3]
  const float* Wo = (const float*)d_in[3];  // [2048,2048]
  float* out = (float*)d_out;               // [2,4096,2048] fp32

  char* ws = (char*)d_ws;
  _Float16* Xh   = (_Float16*)(ws);                    // 33,554,432 B
  _Float16* Wih  = (_Float16*)(ws + 33554432);         // 25,165,824 B
  _Float16* Woh  = (_Float16*)(ws + 58720256);         //  8,388,608 B
  _Float16* BCxh = (_Float16*)(ws + 67108864);         // 100,663,296 B
  _Float16* Yh   = (_Float16*)(ws + 167772160);        // 33,554,432 B
  (void)ws_size; (void)in_sizes; (void)n_in; (void)out_size;

  // one fused convert kernel: 33,554,432 elems / 8 per thread / 256 = 16384 blocks
  cvt_all<<<dim3(16384), 256, 0, stream>>>(X, Wi, Wo, Xh, Wih, Woh);

  // in_proj: [8192,2048] x [6144,2048]^T -> BCx fp16   (32 x 24 = 768 blocks)
  gemm8p<_Float16><<<dim3(768), 512, 0, stream>>>(Xh, Wih, BCxh, 6144, 2048, 24);

  conv_gate<<<dim3(1024), 256, 0, stream>>>(BCxh, Wc, Yh);

  // out_proj: [8192,2048] x [2048,2048]^T -> out fp32  (32 x 8 = 256 blocks; N=2048)
  gemm8p<float><<<dim3(256), 512, 0, stream>>>(Yh, Woh, out, 2048, 2048, 8);
}

// Round 11
// 308.336 us; speedup vs baseline: 1.0017x; 1.0017x over previous
//
#include <hip/hip_runtime.h>
#include <hip/hip_fp16.h>

// LFM2 short-conv block. Round 10: ONE barrier per K-tile (was 4). Stages issued at
// tile top, drained by a fully-aged vmcnt(0) at tile end; quadrant MFMAs synced only
// by wave-local lgkmcnt(0). Register choreography identical to r9 (VGPR 112, no spill).

typedef _Float16 f16x8 __attribute__((ext_vector_type(8)));
typedef float    f32x4 __attribute__((ext_vector_type(4)));

#define GLD_LDS16(gsrc, sdst) \
  __builtin_amdgcn_global_load_lds((const __attribute__((address_space(1))) void*)(gsrc), \
                                   (__attribute__((address_space(3))) void*)(sdst), 16, 0, 0)

#define VMCNT0 asm volatile("s_waitcnt vmcnt(0)" ::: "memory")
#define LGKM0  asm volatile("s_waitcnt lgkmcnt(0)" ::: "memory")
#define BAR    __builtin_amdgcn_s_barrier()
#define SCHED0 __builtin_amdgcn_sched_barrier(0)

// ---------------- fused fp32 -> fp16 convert of X, W_in, W_out ----------------
__global__ __launch_bounds__(256) void cvt_all(const float* __restrict__ X,
                                               const float* __restrict__ Wi,
                                               const float* __restrict__ Wo,
                                               _Float16* __restrict__ Xh,
                                               _Float16* __restrict__ Wih,
                                               _Float16* __restrict__ Woh) {
  int base = (blockIdx.x * 256 + threadIdx.x) * 8;   // total 33,554,432 elems
  const float* src;
  _Float16* dst;
  int off;
  if (base < 16777216)      { src = X;  dst = Xh;  off = base; }
  else if (base < 29360128) { src = Wi; dst = Wih; off = base - 16777216; }
  else                      { src = Wo; dst = Woh; off = base - 29360128; }
  const float4* p = reinterpret_cast<const float4*>(src + off);
  float4 a = p[0], b = p[1];
  f16x8 o;
  o[0] = (_Float16)a.x; o[1] = (_Float16)a.y; o[2] = (_Float16)a.z; o[3] = (_Float16)a.w;
  o[4] = (_Float16)b.x; o[5] = (_Float16)b.y; o[6] = (_Float16)b.z; o[7] = (_Float16)b.w;
  *reinterpret_cast<f16x8*>(dst + off) = o;
}

// ---------------- conv + gating: y = Cg * causal_conv3(Bg * x) ----------------
__global__ __launch_bounds__(256) void conv_gate(const _Float16* __restrict__ BCx,
                                                 const float* __restrict__ Wc,   // [2048,1,3]
                                                 _Float16* __restrict__ Y) {
  const int h0 = threadIdx.x * 8;
  const int r0 = blockIdx.x * 8;
  const int s0 = r0 & 4095;

  float w0[8], w1[8], w2[8];
#pragma unroll
  for (int j = 0; j < 8; ++j) {
    w0[j] = Wc[(h0 + j) * 3 + 0];
    w1[j] = Wc[(h0 + j) * 3 + 1];
    w2[j] = Wc[(h0 + j) * 3 + 2];
  }

  float bxm2[8] = {}, bxm1[8] = {};
  if (s0 != 0) {
    const _Float16* pm2 = BCx + (size_t)(r0 - 2) * 6144 + h0;
    const _Float16* pm1 = BCx + (size_t)(r0 - 1) * 6144 + h0;
    f16x8 bg2 = *reinterpret_cast<const f16x8*>(pm2);
    f16x8 xx2 = *reinterpret_cast<const f16x8*>(pm2 + 4096);
    f16x8 bg1 = *reinterpret_cast<const f16x8*>(pm1);
    f16x8 xx1 = *reinterpret_cast<const f16x8*>(pm1 + 4096);
#pragma unroll
    for (int j = 0; j < 8; ++j) {
      bxm2[j] = (float)bg2[j] * (float)xx2[j];
      bxm1[j] = (float)bg1[j] * (float)xx1[j];
    }
  }

  for (int i = 0; i < 8; ++i) {
    const _Float16* pr = BCx + (size_t)(r0 + i) * 6144 + h0;
    f16x8 bg = *reinterpret_cast<const f16x8*>(pr);
    f16x8 cg = *reinterpret_cast<const f16x8*>(pr + 2048);
    f16x8 xx = *reinterpret_cast<const f16x8*>(pr + 4096);
    f16x8 o;
#pragma unroll
    for (int j = 0; j < 8; ++j) {
      float bx   = (float)bg[j] * (float)xx[j];
      float conv = w0[j] * bxm2[j] + w1[j] * bxm1[j] + w2[j] * bx;
      o[j] = (_Float16)((float)cg[j] * conv);
      bxm2[j] = bxm1[j];
      bxm1[j] = bx;
    }
    *reinterpret_cast<f16x8*>(Y + (size_t)(r0 + i) * 2048 + h0) = o;
  }
}

// ---------------- fragment load helpers ----------------
__device__ __forceinline__ void ldA(f16x8 (&af)[4][2], const _Float16* p, int base, int ak0, int ak1) {
#pragma unroll
  for (int i = 0; i < 4; ++i) {
    af[i][0] = *(const f16x8*)(p + base + i * 1024 + ak0);
    af[i][1] = *(const f16x8*)(p + base + i * 1024 + ak1);
  }
}
__device__ __forceinline__ void ldB(f16x8 (&bf)[2][2], const _Float16* p, int base, int ak0, int ak1) {
#pragma unroll
  for (int j = 0; j < 2; ++j) {
    bf[j][0] = *(const f16x8*)(p + base + j * 1024 + ak0);
    bf[j][1] = *(const f16x8*)(p + base + j * 1024 + ak1);
  }
}
template <int QM, int QN>
__device__ __forceinline__ void mfmaQ(f32x4 (&acc)[8][4], const f16x8 (&af)[4][2], const f16x8 (&bf)[2][2]) {
  __builtin_amdgcn_s_setprio(1);
#pragma unroll
  for (int i = 0; i < 4; ++i)
#pragma unroll
    for (int j = 0; j < 2; ++j)
#pragma unroll
      for (int ks = 0; ks < 2; ++ks)
        acc[QM * 4 + i][QN * 2 + j] =
            __builtin_amdgcn_mfma_f32_16x16x32_f16(af[i][ks], bf[j][ks], acc[QM * 4 + i][QN * 2 + j], 0, 0, 0);
  __builtin_amdgcn_s_setprio(0);
}

// 256x256 NT GEMM, BK=64, 8 waves (2x4), 16x16x32 MFMA, 128KB static LDS.
// A LDS [256][64] fp16, phys 16B-chunk ^= (row&7) [T2]; gld_lds linear dest +
// inverse-swizzled per-lane SOURCE (rule 21).
// ONE barrier per tile. Tile body:
//   1. stage all 8 DMA units -> next buffer          (issued EARLY)
//   2. lgkm0; Q00(afL,bf0); ldB bf<-bf1(c)
//   3. lgkm0; Q01(afL,bf1); ldA af<-afH(c)
//   4. lgkm0; Q11(afH,bf1); ldB bf<-bf0(c)
//   5. lgkm0; Q10(afH,bf0)
//   6. vmcnt(0)  [stages aged ~3000 cy -> free]; BAR  [publishes next buffer]
//   7. ldA af<-afL(next); ldB bf<-bf0(next)           (prefetch for next tile)
// Cross-wave audit: all current-buffer reads lgkm-complete before each wave's BAR
// arrival (step-5 lgkm0); stages into next retired by own vmcnt0 pre-BAR; overwrite
// of current happens next tile AFTER the barrier. Every dependency spans the BAR.
// ARGS: N = C column stride, K = reduction dim, nbn = N/256.
template <typename CT>
__global__ __launch_bounds__(512, 2) void gemm8p(const _Float16* __restrict__ Ag,
                                                 const _Float16* __restrict__ Bg,
                                                 CT* __restrict__ Cg,
                                                 int N, int K, int nbn) {
  __shared__ __align__(16) char smem[131072];
  const int tid = threadIdx.x, lane = tid & 63, w = tid >> 6;
  const int wr = w >> 2, wc = w & 3;

  // T1: XCD-bijective block swizzle (grid % 8 == 0)
  const int nwg = (int)gridDim.x, q8 = nwg >> 3;
  const int swz = ((int)blockIdx.x & 7) * q8 + ((int)blockIdx.x >> 3);
  const int bm = (swz / nbn) << 8, bn = (swz % nbn) << 8;

  _Float16* const A0 = (_Float16*)(smem);
  _Float16* const B0 = (_Float16*)(smem + 32768);
  _Float16* const A1 = (_Float16*)(smem + 65536);
  _Float16* const B1 = (_Float16*)(smem + 98304);

  const int rr = tid >> 3;
  const int sCol = ((tid & 7) ^ (rr & 7)) * 8;                  // inverse-swizzled source chunk
  const _Float16* aSrc = Ag + (size_t)(bm + rr) * K + sCol;
  const _Float16* bSrc = Bg + (size_t)(bn + (rr >> 5) * 64 + (rr & 31)) * K + sCol;

  // read-side swizzle folds to per-lane constants (row&7 == lane&7 for all read rows)
  const int ak0 = ((lane >> 4) ^ (lane & 7)) * 8;
  const int ak1 = (((lane >> 4) + 4) ^ (lane & 7)) * 8;
  const int aRB = (wr * 128 + (lane & 15)) * 64;
  const int bRB = (wc * 32 + (lane & 15)) * 64;

  const int nt = K >> 6;

#define STG_A(NBO, kt, u) GLD_LDS16(aSrc + (size_t)(u) * 64 * K + (kt) * 64, \
                                    smem + (NBO) + (u) * 8192 + tid * 16)
#define STG_B(NBO, kt, u) GLD_LDS16(bSrc + (size_t)(((u) & 1) * 128 + ((u) >> 1) * 32) * K + (kt) * 64, \
                                    smem + (NBO) + 32768 + (u) * 8192 + tid * 16)

  f16x8 af[4][2], bf[2][2];
  f32x4 acc[8][4] = {};

  // prologue: stage tile 0 -> buffer 0, drain, pre-read afL(0), bf0(0)
  STG_A(0, 0, 0); STG_A(0, 0, 2);
  STG_B(0, 0, 0); STG_B(0, 0, 1);
  STG_B(0, 0, 2); STG_B(0, 0, 3);
  STG_A(0, 0, 1); STG_A(0, 0, 3);
  VMCNT0; BAR;
  ldA(af, A0, aRB, ak0, ak1);
  ldB(bf, B0, bRB, ak0, ak1);

#define TILE(AB, BB, ABn, BBn, NBO, t)                             \
  {                                                                \
    const int tn = ((t) + 1 < nt) ? (t) + 1 : nt - 1;              \
    /* 1: stage whole next tile into next buffer */                \
    STG_A(NBO, tn, 0); STG_A(NBO, tn, 2);                          \
    STG_B(NBO, tn, 0); STG_B(NBO, tn, 1);                          \
    STG_B(NBO, tn, 2); STG_B(NBO, tn, 3);                          \
    STG_A(NBO, tn, 1); STG_A(NBO, tn, 3);                          \
    /* 2: Q00(afL,bf0); reload bf<-bf1(c) */                       \
    LGKM0; SCHED0;                                                 \
    mfmaQ<0, 0>(acc, af, bf);                                      \
    ldB(bf, BB, bRB + 8192, ak0, ak1);                             \
    /* 3: Q01(afL,bf1); reload af<-afH(c) */                       \
    LGKM0; SCHED0;                                                 \
    mfmaQ<0, 1>(acc, af, bf);                                      \
    ldA(af, AB, aRB + 4096, ak0, ak1);                             \
    /* 4: Q11(afH,bf1); reload bf<-bf0(c) */                       \
    LGKM0; SCHED0;                                                 \
    mfmaQ<1, 1>(acc, af, bf);                                      \
    ldB(bf, BB, bRB, ak0, ak1);                                    \
    /* 5: Q10(afH,bf0) */                                          \
    LGKM0; SCHED0;                                                 \
    mfmaQ<1, 0>(acc, af, bf);                                      \
    /* 6: aged drain + single barrier (publishes next buffer) */   \
    VMCNT0; BAR;                                                   \
    /* 7: prefetch next tile's afL, bf0 from next buffer */        \
    ldA(af, ABn, aRB, ak0, ak1);                                   \
    ldB(bf, BBn, bRB, ak0, ak1);                                   \
  }

  for (int t = 0; t < nt; t += 2) {
    TILE(A0, B0, A1, B1, 65536, t);
    TILE(A1, B1, A0, B0, 0, t + 1);
  }
  LGKM0; VMCNT0;  // drain trailing prefetch reads + tail restage

  // epilogue: D row=(lane>>4)*4+reg, col=lane&15
  const int rb = bm + wr * 128 + ((lane >> 4) << 2);
  const int cb = bn + wc * 64 + (lane & 15);
#pragma unroll
  for (int mi = 0; mi < 8; ++mi)
#pragma unroll
    for (int nj = 0; nj < 4; ++nj) {
      f32x4 v = acc[mi][nj];
#pragma unroll
      for (int rg = 0; rg < 4; ++rg)
        Cg[(size_t)(rb + mi * 16 + rg) * N + cb + nj * 16] = (CT)v[rg];
    }
#undef TILE
#undef STG_A
#undef STG_B
}

// ---------------- launcher ----------------
extern "C" void kernel_launch(void* const* d_in, const int* in_sizes, int n_in,
                              void* d_out, int out_size, void* d_ws, size_t ws_size,
                              hipStream_t stream) {
  const float* X  = (const float*)d_in[0];  // [2,4096,2048]
  const float* Wi = (const float*)d_in[1];  // [6144,2048]
  const float* Wc = (const float*)d_in[2];  // [2048,1,3]
  const float* Wo = (const float*)d_in[3];  // [2048,2048]
  float* out = (float*)d_out;               // [2,4096,2048] fp32

  char* ws = (char*)d_ws;
  _Float16* Xh   = (_Float16*)(ws);                    // 33,554,432 B
  _Float16* Wih  = (_Float16*)(ws + 33554432);         // 25,165,824 B
  _Float16* Woh  = (_Float16*)(ws + 58720256);         //  8,388,608 B
  _Float16* BCxh = (_Float16*)(ws + 67108864);         // 100,663,296 B
  _Float16* Yh   = (_Float16*)(ws + 167772160);        // 33,554,432 B
  (void)ws_size; (void)in_sizes; (void)n_in; (void)out_size;

  // one fused convert kernel: 33,554,432 elems / 8 per thread / 256 = 16384 blocks
  cvt_all<<<dim3(16384), 256, 0, stream>>>(X, Wi, Wo, Xh, Wih, Woh);

  // in_proj: [8192,2048] x [6144,2048]^T -> BCx fp16   (32 x 24 = 768 blocks)
  gemm8p<_Float16><<<dim3(768), 512, 0, stream>>>(Xh, Wih, BCxh, 6144, 2048, 24);

  conv_gate<<<dim3(1024), 256, 0, stream>>>(BCxh, Wc, Yh);

  // out_proj: [8192,2048] x [2048,2048]^T -> out fp32  (32 x 8 = 256 blocks; N=2048)
  gemm8p<float><<<dim3(256), 512, 0, stream>>>(Yh, Woh, out, 2048, 2048, 8);
}

// Round 12
// 301.747 us; speedup vs baseline: 1.0236x; 1.0218x over previous
//
#include <hip/hip_runtime.h>
#include <hip/hip_fp16.h>

// LFM2 short-conv block. Round 12: r8's fully-independent fragment double-buffering
// (loads never overwrite registers still consumed by the current window's MFMAs ->
// no WAR serialization) + __launch_bounds__(512,1). r8's spill came from the 2nd
// launch_bounds arg (min BLOCKS/CU=2 -> 128-VGPR budget); LDS allows only 1 block/CU
// anyway, so min=1 raises the budget to 256 and the extra fragment sets fit.

typedef _Float16 f16x8 __attribute__((ext_vector_type(8)));
typedef float    f32x4 __attribute__((ext_vector_type(4)));

#define GLD_LDS16(gsrc, sdst) \
  __builtin_amdgcn_global_load_lds((const __attribute__((address_space(1))) void*)(gsrc), \
                                   (__attribute__((address_space(3))) void*)(sdst), 16, 0, 0)

#define VMCNT2 asm volatile("s_waitcnt vmcnt(2)" ::: "memory")
#define VMCNT0 asm volatile("s_waitcnt vmcnt(0)" ::: "memory")
#define LGKM0  asm volatile("s_waitcnt lgkmcnt(0)" ::: "memory")
#define BAR    __builtin_amdgcn_s_barrier()
#define SCHED0 __builtin_amdgcn_sched_barrier(0)

// ---------------- fused fp32 -> fp16 convert of X, W_in, W_out ----------------
__global__ __launch_bounds__(256) void cvt_all(const float* __restrict__ X,
                                               const float* __restrict__ Wi,
                                               const float* __restrict__ Wo,
                                               _Float16* __restrict__ Xh,
                                               _Float16* __restrict__ Wih,
                                               _Float16* __restrict__ Woh) {
  int base = (blockIdx.x * 256 + threadIdx.x) * 8;   // total 33,554,432 elems
  const float* src;
  _Float16* dst;
  int off;
  if (base < 16777216)      { src = X;  dst = Xh;  off = base; }
  else if (base < 29360128) { src = Wi; dst = Wih; off = base - 16777216; }
  else                      { src = Wo; dst = Woh; off = base - 29360128; }
  const float4* p = reinterpret_cast<const float4*>(src + off);
  float4 a = p[0], b = p[1];
  f16x8 o;
  o[0] = (_Float16)a.x; o[1] = (_Float16)a.y; o[2] = (_Float16)a.z; o[3] = (_Float16)a.w;
  o[4] = (_Float16)b.x; o[5] = (_Float16)b.y; o[6] = (_Float16)b.z; o[7] = (_Float16)b.w;
  *reinterpret_cast<f16x8*>(dst + off) = o;
}

// ---------------- conv + gating: y = Cg * causal_conv3(Bg * x) ----------------
__global__ __launch_bounds__(256) void conv_gate(const _Float16* __restrict__ BCx,
                                                 const float* __restrict__ Wc,   // [2048,1,3]
                                                 _Float16* __restrict__ Y) {
  const int h0 = threadIdx.x * 8;
  const int r0 = blockIdx.x * 8;
  const int s0 = r0 & 4095;

  float w0[8], w1[8], w2[8];
#pragma unroll
  for (int j = 0; j < 8; ++j) {
    w0[j] = Wc[(h0 + j) * 3 + 0];
    w1[j] = Wc[(h0 + j) * 3 + 1];
    w2[j] = Wc[(h0 + j) * 3 + 2];
  }

  float bxm2[8] = {}, bxm1[8] = {};
  if (s0 != 0) {
    const _Float16* pm2 = BCx + (size_t)(r0 - 2) * 6144 + h0;
    const _Float16* pm1 = BCx + (size_t)(r0 - 1) * 6144 + h0;
    f16x8 bg2 = *reinterpret_cast<const f16x8*>(pm2);
    f16x8 xx2 = *reinterpret_cast<const f16x8*>(pm2 + 4096);
    f16x8 bg1 = *reinterpret_cast<const f16x8*>(pm1);
    f16x8 xx1 = *reinterpret_cast<const f16x8*>(pm1 + 4096);
#pragma unroll
    for (int j = 0; j < 8; ++j) {
      bxm2[j] = (float)bg2[j] * (float)xx2[j];
      bxm1[j] = (float)bg1[j] * (float)xx1[j];
    }
  }

  for (int i = 0; i < 8; ++i) {
    const _Float16* pr = BCx + (size_t)(r0 + i) * 6144 + h0;
    f16x8 bg = *reinterpret_cast<const f16x8*>(pr);
    f16x8 cg = *reinterpret_cast<const f16x8*>(pr + 2048);
    f16x8 xx = *reinterpret_cast<const f16x8*>(pr + 4096);
    f16x8 o;
#pragma unroll
    for (int j = 0; j < 8; ++j) {
      float bx   = (float)bg[j] * (float)xx[j];
      float conv = w0[j] * bxm2[j] + w1[j] * bxm1[j] + w2[j] * bx;
      o[j] = (_Float16)((float)cg[j] * conv);
      bxm2[j] = bxm1[j];
      bxm1[j] = bx;
    }
    *reinterpret_cast<f16x8*>(Y + (size_t)(r0 + i) * 2048 + h0) = o;
  }
}

// ---------------- fragment load helpers ----------------
__device__ __forceinline__ void ldA(f16x8 (&af)[4][2], const _Float16* p, int base, int ak0, int ak1) {
#pragma unroll
  for (int i = 0; i < 4; ++i) {
    af[i][0] = *(const f16x8*)(p + base + i * 1024 + ak0);
    af[i][1] = *(const f16x8*)(p + base + i * 1024 + ak1);
  }
}
__device__ __forceinline__ void ldB(f16x8 (&bf)[2][2], const _Float16* p, int base, int ak0, int ak1) {
#pragma unroll
  for (int j = 0; j < 2; ++j) {
    bf[j][0] = *(const f16x8*)(p + base + j * 1024 + ak0);
    bf[j][1] = *(const f16x8*)(p + base + j * 1024 + ak1);
  }
}
template <int QM, int QN>
__device__ __forceinline__ void mfmaQ(f32x4 (&acc)[8][4], const f16x8 (&af)[4][2], const f16x8 (&bf)[2][2]) {
  __builtin_amdgcn_s_setprio(1);
#pragma unroll
  for (int i = 0; i < 4; ++i)
#pragma unroll
    for (int j = 0; j < 2; ++j)
#pragma unroll
      for (int ks = 0; ks < 2; ++ks)
        acc[QM * 4 + i][QN * 2 + j] =
            __builtin_amdgcn_mfma_f32_16x16x32_f16(af[i][ks], bf[j][ks], acc[QM * 4 + i][QN * 2 + j], 0, 0, 0);
  __builtin_amdgcn_s_setprio(0);
}

// 256x256 NT GEMM, BK=64, 8 waves (2x4), 16x16x32 MFMA, 128KB static LDS.
// A LDS [256][64] fp16, phys 16B-chunk ^= (row&7) [T2]; gld_lds linear dest +
// inverse-swizzled per-lane SOURCE (rule 21).
// Window (1 barrier each): {LGKM0; SCHED0; loads(W+1 frags, INDEPENDENT regs);
// MFMA(frags loaded W-1); stage 2 DMA; VMCNT2; BAR}.
// Loads:  W0: bfB<-bf1(t); W1: afH(t); W2: afL(t+1) [next buf]; W3: bf0(t+1)->rot.
// MFMA:   W0: Q00(afL,bf0) W1: Q01(afL,bfB) W2: Q11(afH,bfB) W3: Q10(afH,bf0).
// Stages: W0: a'{0,2}; W1: b'{0,1}; W2: b'{2,3}; W3: a'{1,3}; vmcnt(2) each end ->
// unit staged in W retired end-(W+1), published by that BAR, read W+2 (ledger from
// r8, which passed dual validation). bf0 sets rotated by the 2-tile unroll (bfA/bfC).
// ARGS: N = C column stride, K = reduction dim, nbn = N/256.
template <typename CT>
__global__ __launch_bounds__(512, 1) void gemm8p(const _Float16* __restrict__ Ag,
                                                 const _Float16* __restrict__ Bg,
                                                 CT* __restrict__ Cg,
                                                 int N, int K, int nbn) {
  __shared__ __align__(16) char smem[131072];
  const int tid = threadIdx.x, lane = tid & 63, w = tid >> 6;
  const int wr = w >> 2, wc = w & 3;

  // T1: XCD-bijective block swizzle (grid % 8 == 0)
  const int nwg = (int)gridDim.x, q8 = nwg >> 3;
  const int swz = ((int)blockIdx.x & 7) * q8 + ((int)blockIdx.x >> 3);
  const int bm = (swz / nbn) << 8, bn = (swz % nbn) << 8;

  _Float16* const A0 = (_Float16*)(smem);
  _Float16* const B0 = (_Float16*)(smem + 32768);
  _Float16* const A1 = (_Float16*)(smem + 65536);
  _Float16* const B1 = (_Float16*)(smem + 98304);

  const int rr = tid >> 3;
  const int sCol = ((tid & 7) ^ (rr & 7)) * 8;                  // inverse-swizzled source chunk
  const _Float16* aSrc = Ag + (size_t)(bm + rr) * K + sCol;
  const _Float16* bSrc = Bg + (size_t)(bn + (rr >> 5) * 64 + (rr & 31)) * K + sCol;

  // read-side swizzle folds to per-lane constants (row&7 == lane&7 for all read rows)
  const int ak0 = ((lane >> 4) ^ (lane & 7)) * 8;
  const int ak1 = (((lane >> 4) + 4) ^ (lane & 7)) * 8;
  const int aRB = (wr * 128 + (lane & 15)) * 64;
  const int bRB = (wc * 32 + (lane & 15)) * 64;

  const int nt = K >> 6;

#define STG_A(NBO, kt, u) GLD_LDS16(aSrc + (size_t)(u) * 64 * K + (kt) * 64, \
                                    smem + (NBO) + (u) * 8192 + tid * 16)
#define STG_B(NBO, kt, u) GLD_LDS16(bSrc + (size_t)(((u) & 1) * 128 + ((u) >> 1) * 32) * K + (kt) * 64, \
                                    smem + (NBO) + 32768 + (u) * 8192 + tid * 16)

  f16x8 afL[4][2], afH[4][2];             // A low/high halves of current tile
  f16x8 bfA[2][2], bfB[2][2], bfC[2][2];  // bf0 even / bf1 shared / bf0 odd
  f32x4 acc[8][4] = {};

  // prologue: stage tile 0 -> buffer 0, drain, pre-read afL(0), bf0(0)
  STG_A(0, 0, 0); STG_A(0, 0, 2);
  STG_B(0, 0, 0); STG_B(0, 0, 1);
  STG_B(0, 0, 2); STG_B(0, 0, 3);
  STG_A(0, 0, 1); STG_A(0, 0, 3);
  VMCNT0; BAR;
  ldA(afL, A0, aRB, ak0, ak1);
  ldB(bfA, B0, bRB, ak0, ak1);

#define TILE(AB, BB, ABn, BBn, NBO, t, BF0, BF0N)                  \
  {                                                                \
    const int tn = ((t) + 1 < nt) ? (t) + 1 : nt - 1;              \
    /* W0: loads bf1(t); MFMA Q00; stage a02' */                   \
    LGKM0; SCHED0;                                                 \
    ldB(bfB, BB, bRB + 8192, ak0, ak1);                            \
    mfmaQ<0, 0>(acc, afL, BF0);                                    \
    STG_A(NBO, tn, 0); STG_A(NBO, tn, 2);                          \
    VMCNT2; BAR;                                                   \
    /* W1: loads afH(t); MFMA Q01; stage b01' */                   \
    LGKM0; SCHED0;                                                 \
    ldA(afH, AB, aRB + 4096, ak0, ak1);                            \
    mfmaQ<0, 1>(acc, afL, bfB);                                    \
    STG_B(NBO, tn, 0); STG_B(NBO, tn, 1);                          \
    VMCNT2; BAR;                                                   \
    /* W2: loads afL(t+1) [next buf]; MFMA Q11; stage b23' */      \
    LGKM0; SCHED0;                                                 \
    ldA(afL, ABn, aRB, ak0, ak1);                                  \
    mfmaQ<1, 1>(acc, afH, bfB);                                    \
    STG_B(NBO, tn, 2); STG_B(NBO, tn, 3);                          \
    VMCNT2; BAR;                                                   \
    /* W3: loads bf0(t+1) [next buf, rotated set]; MFMA Q10; stage a13' */ \
    LGKM0; SCHED0;                                                 \
    ldB(BF0N, BBn, bRB, ak0, ak1);                                 \
    mfmaQ<1, 0>(acc, afH, BF0);                                    \
    STG_A(NBO, tn, 1); STG_A(NBO, tn, 3);                          \
    VMCNT2; BAR;                                                   \
  }

  for (int t = 0; t < nt; t += 2) {
    TILE(A0, B0, A1, B1, 65536, t,     bfA, bfC);
    TILE(A1, B1, A0, B0, 0,     t + 1, bfC, bfA);
  }
  LGKM0; VMCNT0;  // drain trailing prefetch reads + tail restage

  // epilogue: D row=(lane>>4)*4+reg, col=lane&15
  const int rb = bm + wr * 128 + ((lane >> 4) << 2);
  const int cb = bn + wc * 64 + (lane & 15);
#pragma unroll
  for (int mi = 0; mi < 8; ++mi)
#pragma unroll
    for (int nj = 0; nj < 4; ++nj) {
      f32x4 v = acc[mi][nj];
#pragma unroll
      for (int rg = 0; rg < 4; ++rg)
        Cg[(size_t)(rb + mi * 16 + rg) * N + cb + nj * 16] = (CT)v[rg];
    }
#undef TILE
#undef STG_A
#undef STG_B
}

// ---------------- launcher ----------------
extern "C" void kernel_launch(void* const* d_in, const int* in_sizes, int n_in,
                              void* d_out, int out_size, void* d_ws, size_t ws_size,
                              hipStream_t stream) {
  const float* X  = (const float*)d_in[0];  // [2,4096,2048]
  const float* Wi = (const float*)d_in[1];  // [6144,2048]
  const float* Wc = (const float*)d_in[2];  // [2048,1,3]
  const float* Wo = (const float*)d_in[3];  // [2048,2048]
  float* out = (float*)d_out;               // [2,4096,2048] fp32

  char* ws = (char*)d_ws;
  _Float16* Xh   = (_Float16*)(ws);                    // 33,554,432 B
  _Float16* Wih  = (_Float16*)(ws + 33554432);         // 25,165,824 B
  _Float16* Woh  = (_Float16*)(ws + 58720256);         //  8,388,608 B
  _Float16* BCxh = (_Float16*)(ws + 67108864);         // 100,663,296 B
  _Float16* Yh   = (_Float16*)(ws + 167772160);        // 33,554,432 B
  (void)ws_size; (void)in_sizes; (void)n_in; (void)out_size;

  // one fused convert kernel: 33,554,432 elems / 8 per thread / 256 = 16384 blocks
  cvt_all<<<dim3(16384), 256, 0, stream>>>(X, Wi, Wo, Xh, Wih, Woh);

  // in_proj: [8192,2048] x [6144,2048]^T -> BCx fp16   (32 x 24 = 768 blocks)
  gemm8p<_Float16><<<dim3(768), 512, 0, stream>>>(Xh, Wih, BCxh, 6144, 2048, 24);

  conv_gate<<<dim3(1024), 256, 0, stream>>>(BCxh, Wc, Yh);

  // out_proj: [8192,2048] x [2048,2048]^T -> out fp32  (32 x 8 = 256 blocks; N=2048)
  gemm8p<float><<<dim3(256), 512, 0, stream>>>(Yh, Woh, out, 2048, 2048, 8);
}

// Round 13
// 296.377 us; speedup vs baseline: 1.0421x; 1.0181x over previous
//
#include <hip/hip_runtime.h>
#include <hip/hip_fp16.h>

// LFM2 short-conv block. Round 13: r7's schedule, but WITHOUT manual lgkmcnt(0)+
// sched_barrier(0) before MFMA -- the compiler emits fine-grained lgkmcnt(N) so
// MFMAs interleave with the read burst (m97 evidence). Compiler-only fences keep
// the C++ ds_reads inside their phase (raw s_barrier is not an optimizer fence).

typedef _Float16 f16x8 __attribute__((ext_vector_type(8)));
typedef float    f32x4 __attribute__((ext_vector_type(4)));

#define GLD_LDS16(gsrc, sdst) \
  __builtin_amdgcn_global_load_lds((const __attribute__((address_space(1))) void*)(gsrc), \
                                   (__attribute__((address_space(3))) void*)(sdst), 16, 0, 0)

#define VMCNT4 asm volatile("s_waitcnt vmcnt(4)" ::: "memory")
#define VMCNT0 asm volatile("s_waitcnt vmcnt(0)" ::: "memory")
#define LGKM0  asm volatile("s_waitcnt lgkmcnt(0)" ::: "memory")
#define BAR    __builtin_amdgcn_s_barrier()
#define FENCE  asm volatile("" ::: "memory")   // compiler-only; no instruction

// ---------------- fused fp32 -> fp16 convert of X, W_in, W_out ----------------
__global__ __launch_bounds__(256) void cvt_all(const float* __restrict__ X,
                                               const float* __restrict__ Wi,
                                               const float* __restrict__ Wo,
                                               _Float16* __restrict__ Xh,
                                               _Float16* __restrict__ Wih,
                                               _Float16* __restrict__ Woh) {
  int base = (blockIdx.x * 256 + threadIdx.x) * 8;   // total 33,554,432 elems
  const float* src;
  _Float16* dst;
  int off;
  if (base < 16777216)      { src = X;  dst = Xh;  off = base; }
  else if (base < 29360128) { src = Wi; dst = Wih; off = base - 16777216; }
  else                      { src = Wo; dst = Woh; off = base - 29360128; }
  const float4* p = reinterpret_cast<const float4*>(src + off);
  float4 a = p[0], b = p[1];
  f16x8 o;
  o[0] = (_Float16)a.x; o[1] = (_Float16)a.y; o[2] = (_Float16)a.z; o[3] = (_Float16)a.w;
  o[4] = (_Float16)b.x; o[5] = (_Float16)b.y; o[6] = (_Float16)b.z; o[7] = (_Float16)b.w;
  *reinterpret_cast<f16x8*>(dst + off) = o;
}

// ---------------- conv + gating: y = Cg * causal_conv3(Bg * x) ----------------
__global__ __launch_bounds__(256) void conv_gate(const _Float16* __restrict__ BCx,
                                                 const float* __restrict__ Wc,   // [2048,1,3]
                                                 _Float16* __restrict__ Y) {
  const int h0 = threadIdx.x * 8;
  const int r0 = blockIdx.x * 8;
  const int s0 = r0 & 4095;

  float w0[8], w1[8], w2[8];
#pragma unroll
  for (int j = 0; j < 8; ++j) {
    w0[j] = Wc[(h0 + j) * 3 + 0];
    w1[j] = Wc[(h0 + j) * 3 + 1];
    w2[j] = Wc[(h0 + j) * 3 + 2];
  }

  float bxm2[8] = {}, bxm1[8] = {};
  if (s0 != 0) {
    const _Float16* pm2 = BCx + (size_t)(r0 - 2) * 6144 + h0;
    const _Float16* pm1 = BCx + (size_t)(r0 - 1) * 6144 + h0;
    f16x8 bg2 = *reinterpret_cast<const f16x8*>(pm2);
    f16x8 xx2 = *reinterpret_cast<const f16x8*>(pm2 + 4096);
    f16x8 bg1 = *reinterpret_cast<const f16x8*>(pm1);
    f16x8 xx1 = *reinterpret_cast<const f16x8*>(pm1 + 4096);
#pragma unroll
    for (int j = 0; j < 8; ++j) {
      bxm2[j] = (float)bg2[j] * (float)xx2[j];
      bxm1[j] = (float)bg1[j] * (float)xx1[j];
    }
  }

  for (int i = 0; i < 8; ++i) {
    const _Float16* pr = BCx + (size_t)(r0 + i) * 6144 + h0;
    f16x8 bg = *reinterpret_cast<const f16x8*>(pr);
    f16x8 cg = *reinterpret_cast<const f16x8*>(pr + 2048);
    f16x8 xx = *reinterpret_cast<const f16x8*>(pr + 4096);
    f16x8 o;
#pragma unroll
    for (int j = 0; j < 8; ++j) {
      float bx   = (float)bg[j] * (float)xx[j];
      float conv = w0[j] * bxm2[j] + w1[j] * bxm1[j] + w2[j] * bx;
      o[j] = (_Float16)((float)cg[j] * conv);
      bxm2[j] = bxm1[j];
      bxm1[j] = bx;
    }
    *reinterpret_cast<f16x8*>(Y + (size_t)(r0 + i) * 2048 + h0) = o;
  }
}

// ---------------- fragment load helpers ----------------
__device__ __forceinline__ void ldA(f16x8 (&af)[4][2], const _Float16* p, int base, int ak0, int ak1) {
#pragma unroll
  for (int i = 0; i < 4; ++i) {
    af[i][0] = *(const f16x8*)(p + base + i * 1024 + ak0);
    af[i][1] = *(const f16x8*)(p + base + i * 1024 + ak1);
  }
}
__device__ __forceinline__ void ldB(f16x8 (&bf)[2][2], const _Float16* p, int base, int ak0, int ak1) {
#pragma unroll
  for (int j = 0; j < 2; ++j) {
    bf[j][0] = *(const f16x8*)(p + base + j * 1024 + ak0);
    bf[j][1] = *(const f16x8*)(p + base + j * 1024 + ak1);
  }
}
template <int QM, int QN>
__device__ __forceinline__ void mfmaQ(f32x4 (&acc)[8][4], const f16x8 (&af)[4][2], const f16x8 (&bf)[2][2]) {
  __builtin_amdgcn_s_setprio(1);
#pragma unroll
  for (int i = 0; i < 4; ++i)
#pragma unroll
    for (int j = 0; j < 2; ++j)
#pragma unroll
      for (int ks = 0; ks < 2; ++ks)
        acc[QM * 4 + i][QN * 2 + j] =
            __builtin_amdgcn_mfma_f32_16x16x32_f16(af[i][ks], bf[j][ks], acc[QM * 4 + i][QN * 2 + j], 0, 0, 0);
  __builtin_amdgcn_s_setprio(0);
}

// 256x256 NT GEMM, BK=64, 8 waves (2x4), 16x16x32 MFMA, 128KB static LDS.
// A LDS [256][64] fp16, phys 16B-chunk ^= (row&7) [T2]; gld_lds linear dest +
// inverse-swizzled per-lane SOURCE (rule 21).
// Phase: {FENCE; reads(p); stage; vmcnt(4); BAR; FENCE; MFMA(p)} -- NO manual
// lgkm drain: the compiler emits fine-grained lgkmcnt(N) so MFMA interleaves
// with the read tail. FENCE pins C++ ds_reads inside their phase (upward:
// after-BAR fence; downward: the memory-clobbering VMCNT/next fence).
// DMA ledger identical to r7 (passed 2x validation): stage order P0:A'{0,2}
// P1:B'{0,1} P2:B'{2,3} P3:A'{1,3}; vmcnt(4) at P0/P1/P3 retires exactly the
// units the next phase reads, before the publishing barrier.
// ARGS: N = C column stride, K = reduction dim, nbn = N/256.
template <typename CT>
__global__ __launch_bounds__(512, 2) void gemm8p(const _Float16* __restrict__ Ag,
                                                 const _Float16* __restrict__ Bg,
                                                 CT* __restrict__ Cg,
                                                 int N, int K, int nbn) {
  __shared__ __align__(16) char smem[131072];
  const int tid = threadIdx.x, lane = tid & 63, w = tid >> 6;
  const int wr = w >> 2, wc = w & 3;

  // T1: XCD-bijective block swizzle (grid % 8 == 0)
  const int nwg = (int)gridDim.x, q8 = nwg >> 3;
  const int swz = ((int)blockIdx.x & 7) * q8 + ((int)blockIdx.x >> 3);
  const int bm = (swz / nbn) << 8, bn = (swz % nbn) << 8;

  _Float16* const A0 = (_Float16*)(smem);
  _Float16* const B0 = (_Float16*)(smem + 32768);
  _Float16* const A1 = (_Float16*)(smem + 65536);
  _Float16* const B1 = (_Float16*)(smem + 98304);

  const int rr = tid >> 3;
  const int sCol = ((tid & 7) ^ (rr & 7)) * 8;                  // inverse-swizzled source chunk
  const _Float16* aSrc = Ag + (size_t)(bm + rr) * K + sCol;
  const _Float16* bSrc = Bg + (size_t)(bn + (rr >> 5) * 64 + (rr & 31)) * K + sCol;

  // read-side swizzle folds to per-lane constants (row&7 == lane&7 for all read rows)
  const int ak0 = ((lane >> 4) ^ (lane & 7)) * 8;
  const int ak1 = (((lane >> 4) + 4) ^ (lane & 7)) * 8;
  const int aRB = (wr * 128 + (lane & 15)) * 64;
  const int bRB = (wc * 32 + (lane & 15)) * 64;

  const int nt = K >> 6;

#define STG_A(NBO, kt, u) GLD_LDS16(aSrc + (size_t)(u) * 64 * K + (kt) * 64, \
                                    smem + (NBO) + (u) * 8192 + tid * 16)
#define STG_B(NBO, kt, u) GLD_LDS16(bSrc + (size_t)(((u) & 1) * 128 + ((u) >> 1) * 32) * K + (kt) * 64, \
                                    smem + (NBO) + 32768 + (u) * 8192 + tid * 16)

  f16x8 af[4][2], bf[2][2];
  f32x4 acc[8][4] = {};

  // prologue: tile 0 -> buffer 0, consumption order A0,A2,B0,B1 | B2,B3,A1,A3
  STG_A(0, 0, 0); STG_A(0, 0, 2);
  STG_B(0, 0, 0); STG_B(0, 0, 1);
  STG_B(0, 0, 2); STG_B(0, 0, 3);
  STG_A(0, 0, 1); STG_A(0, 0, 3);
  VMCNT4; BAR; FENCE;

  // Per tile: 4 phases = C-quadrants (0,0),(0,1),(1,1),(1,0).
#define TILE(AB, BB, NBO, t)                                       \
  {                                                                \
    const int tn = ((t) + 1 < nt) ? (t) + 1 : nt - 1;              \
    /* P0: q=(0,0) */                                              \
    ldA(af, AB, aRB, ak0, ak1);                                    \
    ldB(bf, BB, bRB, ak0, ak1);                                    \
    STG_A(NBO, tn, 0); STG_A(NBO, tn, 2);                          \
    VMCNT4; BAR; FENCE;                                            \
    mfmaQ<0, 0>(acc, af, bf);                                      \
    /* P1: q=(0,1) */                                              \
    ldB(bf, BB, bRB + 8192, ak0, ak1);                             \
    STG_B(NBO, tn, 0); STG_B(NBO, tn, 1);                          \
    VMCNT4; BAR; FENCE;                                            \
    mfmaQ<0, 1>(acc, af, bf);                                      \
    /* P2: q=(1,1) */                                              \
    ldA(af, AB, aRB + 4096, ak0, ak1);                             \
    STG_B(NBO, tn, 2); STG_B(NBO, tn, 3);                          \
    BAR; FENCE;                                                    \
    mfmaQ<1, 1>(acc, af, bf);                                      \
    /* P3: q=(1,0), re-read B half 0 */                            \
    ldB(bf, BB, bRB, ak0, ak1);                                    \
    STG_A(NBO, tn, 1); STG_A(NBO, tn, 3);                          \
    VMCNT4; BAR; FENCE;                                            \
    mfmaQ<1, 0>(acc, af, bf);                                      \
  }

  for (int t = 0; t < nt; t += 2) {
    TILE(A0, B0, 65536, t);
    TILE(A1, B1, 0, t + 1);
  }
  LGKM0; VMCNT0;  // drain LDS-DMA (tail restage never consumed)

  // epilogue: D row=(lane>>4)*4+reg, col=lane&15
  const int rb = bm + wr * 128 + ((lane >> 4) << 2);
  const int cb = bn + wc * 64 + (lane & 15);
#pragma unroll
  for (int mi = 0; mi < 8; ++mi)
#pragma unroll
    for (int nj = 0; nj < 4; ++nj) {
      f32x4 v = acc[mi][nj];
#pragma unroll
      for (int rg = 0; rg < 4; ++rg)
        Cg[(size_t)(rb + mi * 16 + rg) * N + cb + nj * 16] = (CT)v[rg];
    }
#undef TILE
#undef STG_A
#undef STG_B
}

// ---------------- launcher ----------------
extern "C" void kernel_launch(void* const* d_in, const int* in_sizes, int n_in,
                              void* d_out, int out_size, void* d_ws, size_t ws_size,
                              hipStream_t stream) {
  const float* X  = (const float*)d_in[0];  // [2,4096,2048]
  const float* Wi = (const float*)d_in[1];  // [6144,2048]
  const float* Wc = (const float*)d_in[2];  // [2048,1,3]
  const float* Wo = (const float*)d_in[3];  // [2048,2048]
  float* out = (float*)d_out;               // [2,4096,2048] fp32

  char* ws = (char*)d_ws;
  _Float16* Xh   = (_Float16*)(ws);                    // 33,554,432 B
  _Float16* Wih  = (_Float16*)(ws + 33554432);         // 25,165,824 B
  _Float16* Woh  = (_Float16*)(ws + 58720256);         //  8,388,608 B
  _Float16* BCxh = (_Float16*)(ws + 67108864);         // 100,663,296 B
  _Float16* Yh   = (_Float16*)(ws + 167772160);        // 33,554,432 B
  (void)ws_size; (void)in_sizes; (void)n_in; (void)out_size;

  // one fused convert kernel: 33,554,432 elems / 8 per thread / 256 = 16384 blocks
  cvt_all<<<dim3(16384), 256, 0, stream>>>(X, Wi, Wo, Xh, Wih, Woh);

  // in_proj: [8192,2048] x [6144,2048]^T -> BCx fp16   (32 x 24 = 768 blocks)
  gemm8p<_Float16><<<dim3(768), 512, 0, stream>>>(Xh, Wih, BCxh, 6144, 2048, 24);

  conv_gate<<<dim3(1024), 256, 0, stream>>>(BCxh, Wc, Yh);

  // out_proj: [8192,2048] x [2048,2048]^T -> out fp32  (32 x 8 = 256 blocks; N=2048)
  gemm8p<float><<<dim3(256), 512, 0, stream>>>(Yh, Woh, out, 2048, 2048, 8);
}